// Round 5
// baseline (2110.847 us; speedup 1.0000x reference)
//
#include <hip/hip_runtime.h>
#include <hip/hip_bf16.h>
#include <stdint.h>

#define LNUM 6
#define BB 8
#define TT 1024
#define CC 768
#define HH 12
#define HDIM 64
#define DFF 3072
#define VV 512
#define MM (BB*TT)
#define QKREG ((size_t)BB*HH*TT*64)

typedef __bf16 bf16x8 __attribute__((ext_vector_type(8)));
typedef float f32x4 __attribute__((ext_vector_type(4)));

__device__ __forceinline__ uint16_t f2b(float f) {
  uint32_t u = __float_as_uint(f);
  u += 0x7FFFu + ((u >> 16) & 1u);
  return (uint16_t)(u >> 16);
}

__device__ __forceinline__ void gld16(const uint16_t* g, uint16_t* l) {
  __builtin_amdgcn_global_load_lds(
      (const __attribute__((address_space(1))) uint32_t*)g,
      (__attribute__((address_space(3))) uint32_t*)l, 16, 0, 0);
}

__device__ __forceinline__ f32x4 mfma16(bf16x8 a, bf16x8 b, f32x4 c) {
  return __builtin_amdgcn_mfma_f32_16x16x32_bf16(a, b, c, 0, 0, 0);
}

// ---------------- convert f32 -> bf16 ----------------
__global__ __launch_bounds__(256) void cvt4_k(const float* __restrict__ in,
                                              uint16_t* __restrict__ out, int n4) {
  const int gid = blockIdx.x * 256 + threadIdx.x;
  if (gid >= n4) return;
  const float4 v = ((const float4*)in)[gid];
  ushort4 w; w.x = f2b(v.x); w.y = f2b(v.y); w.z = f2b(v.z); w.w = f2b(v.w);
  ((ushort4*)out)[gid] = w;
}

// ---------------- embedding ----------------
__global__ __launch_bounds__(256) void embed_k(const int* __restrict__ idx,
                                               const float* __restrict__ tok,
                                               const float* __restrict__ pos,
                                               float* __restrict__ x) {
  const int gid = blockIdx.x * 256 + threadIdx.x;
  const int row = gid / (CC / 4), c4 = gid % (CC / 4);
  const int t = row & (TT - 1);
  const int tkn = idx[row];
  const float4 a = ((const float4*)(tok + (size_t)tkn * CC))[c4];
  const float4 q = ((const float4*)(pos + (size_t)t * CC))[c4];
  ((float4*)(x + (size_t)row * CC))[c4] =
      make_float4(a.x + q.x, a.y + q.y, a.z + q.z, a.w + q.w);
}

// ---------------- layernorm: fp32 in -> bf16 out ----------------
__global__ __launch_bounds__(256) void ln_k(const float* __restrict__ x,
                                            const float* __restrict__ gamma,
                                            const float* __restrict__ beta,
                                            uint16_t* __restrict__ o) {
  const int lane = threadIdx.x & 63, wid = threadIdx.x >> 6;
  const int row = blockIdx.x * 4 + wid;
  const float4* xr = (const float4*)(x + (size_t)row * CC);
  float4 v[3]; float s = 0.f, sq = 0.f;
#pragma unroll
  for (int i = 0; i < 3; ++i) {
    v[i] = xr[lane + i * 64];
    s += v[i].x + v[i].y + v[i].z + v[i].w;
    sq += v[i].x * v[i].x + v[i].y * v[i].y + v[i].z * v[i].z + v[i].w * v[i].w;
  }
#pragma unroll
  for (int m = 1; m < 64; m <<= 1) { s += __shfl_xor(s, m, 64); sq += __shfl_xor(sq, m, 64); }
  const float mu = s * (1.f / 768.f);
  const float rstd = rsqrtf(sq * (1.f / 768.f) - mu * mu + 1e-5f);
  ushort4* orow = (ushort4*)(o + (size_t)row * CC);
#pragma unroll
  for (int i = 0; i < 3; ++i) {
    const int c4 = lane + i * 64;
    const float4 gg = ((const float4*)gamma)[c4];
    const float4 bb = ((const float4*)beta)[c4];
    ushort4 w;
    w.x = f2b((v[i].x - mu) * rstd * gg.x + bb.x);
    w.y = f2b((v[i].y - mu) * rstd * gg.y + bb.y);
    w.z = f2b((v[i].z - mu) * rstd * gg.z + bb.z);
    w.w = f2b((v[i].w - mu) * rstd * gg.w + bb.w);
    orow[c4] = w;
  }
}

// ------- layernorm + partial-sum reduce: x += p0+p1; o = LN(x)  -------
__global__ __launch_bounds__(256) void lnr_k(float* __restrict__ x,
                                             const float* __restrict__ p0,
                                             const float* __restrict__ p1,
                                             const float* __restrict__ gamma,
                                             const float* __restrict__ beta,
                                             uint16_t* __restrict__ o) {
  const int lane = threadIdx.x & 63, wid = threadIdx.x >> 6;
  const int row = blockIdx.x * 4 + wid;
  float4* xr = (float4*)(x + (size_t)row * CC);
  const float4* pr0 = (const float4*)(p0 + (size_t)row * CC);
  const float4* pr1 = (const float4*)(p1 + (size_t)row * CC);
  float4 v[3]; float s = 0.f, sq = 0.f;
#pragma unroll
  for (int i = 0; i < 3; ++i) {
    const int c4 = lane + i * 64;
    float4 a = xr[c4];
    const float4 q0 = pr0[c4];
    const float4 q1 = pr1[c4];
    a.x += q0.x + q1.x; a.y += q0.y + q1.y;
    a.z += q0.z + q1.z; a.w += q0.w + q1.w;
    xr[c4] = a;
    v[i] = a;
    s += a.x + a.y + a.z + a.w;
    sq += a.x * a.x + a.y * a.y + a.z * a.z + a.w * a.w;
  }
#pragma unroll
  for (int m = 1; m < 64; m <<= 1) { s += __shfl_xor(s, m, 64); sq += __shfl_xor(sq, m, 64); }
  const float mu = s * (1.f / 768.f);
  const float rstd = rsqrtf(sq * (1.f / 768.f) - mu * mu + 1e-5f);
  ushort4* orow = (ushort4*)(o + (size_t)row * CC);
#pragma unroll
  for (int i = 0; i < 3; ++i) {
    const int c4 = lane + i * 64;
    const float4 gg = ((const float4*)gamma)[c4];
    const float4 bb = ((const float4*)beta)[c4];
    ushort4 w;
    w.x = f2b((v[i].x - mu) * rstd * gg.x + bb.x);
    w.y = f2b((v[i].y - mu) * rstd * gg.y + bb.y);
    w.z = f2b((v[i].z - mu) * rstd * gg.z + bb.z);
    w.w = f2b((v[i].w - mu) * rstd * gg.w + bb.w);
    orow[c4] = w;
  }
}

// ---------------- transpose+convert weights ----------------
__global__ __launch_bounds__(256) void tconv_k(const float* __restrict__ in,
                                               uint16_t* __restrict__ out, int K, int N) {
  __shared__ float tile[32][33];
  const int kt = blockIdx.x * 32, nt = blockIdx.y * 32;
  const int tx = threadIdx.x & 31, ty = threadIdx.x >> 5;
#pragma unroll
  for (int i = 0; i < 32; i += 8)
    tile[ty + i][tx] = in[(size_t)(kt + ty + i) * N + nt + tx];
  __syncthreads();
#pragma unroll
  for (int i = 0; i < 32; i += 8)
    out[(size_t)(nt + ty + i) * K + kt + tx] = f2b(tile[tx][ty + i]);
}

// ---------------- old 128x128 GEMM (logits + fallback) ----------------
// EPI: 1 = f32 store; 3 = resid +=; 4 = resid += (+bias)
template <int EPI>
__global__ __launch_bounds__(256) void gemm_k(const uint16_t* __restrict__ A,
                                              const uint16_t* __restrict__ Bt,
                                              int N, int K,
                                              const float* __restrict__ bias,
                                              float* __restrict__ resid,
                                              uint16_t* __restrict__ outb,
                                              float* __restrict__ outf) {
  __shared__ __align__(16) uint16_t As[128 * 32];
  __shared__ __align__(16) uint16_t Bs[128 * 32];
  const int lane = threadIdx.x & 63, wid = threadIdx.x >> 6;
  const int wm = wid >> 1, wn = wid & 1;
  const int bm = blockIdx.x * 128, bn = blockIdx.y * 128;
  const int rsub = lane >> 2, csub = (lane & 3) * 8;
  f32x4 acc[4][4] = {};
  for (int k0 = 0; k0 < K; k0 += 32) {
#pragma unroll
    for (int q = 0; q < 2; ++q) {
      const int ch = wid * 2 + q;
      gld16(A + (size_t)(bm + ch * 16 + rsub) * K + k0 + csub, &As[ch * 512]);
      gld16(Bt + (size_t)(bn + ch * 16 + rsub) * K + k0 + csub, &Bs[ch * 512]);
    }
    __syncthreads();
    bf16x8 a[4], b[4];
#pragma unroll
    for (int i = 0; i < 4; ++i) {
      a[i] = *(const bf16x8*)&As[(wm * 64 + i * 16 + (lane & 15)) * 32 + (lane >> 4) * 8];
      b[i] = *(const bf16x8*)&Bs[(wn * 64 + i * 16 + (lane & 15)) * 32 + (lane >> 4) * 8];
    }
#pragma unroll
    for (int i = 0; i < 4; ++i)
#pragma unroll
      for (int j = 0; j < 4; ++j)
        acc[i][j] = mfma16(a[i], b[j], acc[i][j]);
    __syncthreads();
  }
#pragma unroll
  for (int i = 0; i < 4; ++i) {
    const int m0 = bm + wm * 64 + i * 16 + ((lane >> 4) << 2);
#pragma unroll
    for (int j = 0; j < 4; ++j) {
      const int n = bn + wn * 64 + j * 16 + (lane & 15);
#pragma unroll
      for (int r = 0; r < 4; ++r) {
        const size_t o = (size_t)(m0 + r) * N + n;
        const float v = acc[i][j][r];
        if constexpr (EPI == 1) {
          outf[o] = v;
        } else if constexpr (EPI == 3) {
          resid[o] += v;
        } else if constexpr (EPI == 4) {
          resid[o] += v + bias[n];
        }
      }
    }
  }
}

// ======== 256x128-tile, BK=64, triple-buffered, depth-2 prefetch GEMM ========
// 8 waves as 4(M) x 2(N); per-wave 64x64 output (acc 4x4 frags).
// LDS: A 3x32KB + B 3x16KB = 144 KB. 6 loads/thread/K-tile; 18 in flight.
// Swizzle: slot' = slot ^ (row&7) applied on pre-swizzled global source AND
// swizzled read offsets (same involution both sides; gld_lds dest stays linear).
// EPI: 2 = bias+GELU -> bf16; 5 = qkv split; 7 = f32 partial store (+bias kp0)

#define STAGE3(BQ, T)                                                     \
  do {                                                                    \
    const int ko_ = (T) * 64;                                             \
    gld16(gA + ko_,                 &ldsA[BQ][0 * 4096 + (tid << 3)]);    \
    gld16(gA + ko_ + 64 * (size_t)K,  &ldsA[BQ][1 * 4096 + (tid << 3)]);  \
    gld16(gA + ko_ + 128 * (size_t)K, &ldsA[BQ][2 * 4096 + (tid << 3)]);  \
    gld16(gA + ko_ + 192 * (size_t)K, &ldsA[BQ][3 * 4096 + (tid << 3)]);  \
    gld16(gB + ko_,                 &ldsB[BQ][0 * 4096 + (tid << 3)]);    \
    gld16(gB + ko_ + 64 * (size_t)K,  &ldsB[BQ][1 * 4096 + (tid << 3)]);  \
  } while (0)

#define PHASE3(AB, BBp, KK)                                               \
  {                                                                       \
    bf16x8 a_[4], b_[4];                                                  \
    _Pragma("unroll") for (int m_ = 0; m_ < 4; ++m_)                      \
      a_[m_] = *(const bf16x8*)((AB) + aof[KK][m_]);                      \
    _Pragma("unroll") for (int n_ = 0; n_ < 4; ++n_)                      \
      b_[n_] = *(const bf16x8*)((BBp) + bof[KK][n_]);                     \
    asm volatile("s_waitcnt lgkmcnt(0)" ::: "memory");                    \
    __builtin_amdgcn_sched_barrier(0);                                    \
    __builtin_amdgcn_s_setprio(1);                                        \
    _Pragma("unroll") for (int m_ = 0; m_ < 4; ++m_)                      \
      _Pragma("unroll") for (int n_ = 0; n_ < 4; ++n_)                    \
        acc[m_][n_] = mfma16(a_[m_], b_[n_], acc[m_][n_]);                \
    __builtin_amdgcn_s_setprio(0);                                        \
  }

#define TILE3(T, CUR, SB)                                                 \
  do {                                                                    \
    __syncthreads();                                                      \
    if ((T) + 2 < nkt) {                                                  \
      STAGE3(SB, (T) + 2);                                                \
      asm volatile("s_waitcnt vmcnt(12)" ::: "memory");                   \
    } else if ((T) + 1 < nkt) {                                           \
      asm volatile("s_waitcnt vmcnt(6)" ::: "memory");                    \
    } else {                                                              \
      asm volatile("s_waitcnt vmcnt(0)" ::: "memory");                    \
    }                                                                     \
    __builtin_amdgcn_sched_barrier(0);                                    \
    __syncthreads();                                                      \
    {                                                                     \
      const char* Ab_ = (const char*)ldsA[CUR];                           \
      const char* Bb_ = (const char*)ldsB[CUR];                           \
      PHASE3(Ab_, Bb_, 0)                                                 \
      PHASE3(Ab_, Bb_, 1)                                                 \
    }                                                                     \
  } while (0)

template <int EPI>
__global__ __launch_bounds__(512, 2) void gemm3_k(const uint16_t* __restrict__ A,
                                                  const uint16_t* __restrict__ Bt,
                                                  int N, int K, int nbn, int kparts,
                                                  const float* __restrict__ bias,
                                                  uint16_t* __restrict__ outb,
                                                  float* __restrict__ outf) {
  __shared__ uint16_t ldsA[3][16384];
  __shared__ uint16_t ldsB[3][8192];
  const int tid = threadIdx.x, lane = tid & 63, wid = tid >> 6;
  const int l15 = lane & 15, lhi = lane >> 4;
  const int wr = wid >> 1, wc = wid & 1;
  int id = blockIdx.x;
  const int nwg = gridDim.x;
  id = (id & 7) * (nwg >> 3) + (id >> 3);  // XCD swizzle; all grids %8==0
  const int nbmn = nwg / kparts;
  const int kp = id / nbmn;
  const int rid = id - kp * nbmn;
  const int im = rid / nbn, in = rid - im * nbn;
  const int bm = im * 256, bn = in * 128;
  const int Ksub = K / kparts, k0base = kp * Ksub, nkt = Ksub >> 6;  // nkt%3==0
  const int arow = tid >> 3;
  const int aslot = (tid & 7) ^ (arow & 7);
  const uint16_t* gA = A + (size_t)(bm + arow) * K + k0base + aslot * 8;
  const uint16_t* gB = Bt + (size_t)(bn + arow) * K + k0base + aslot * 8;
  const int sw = (l15 & 7) << 4;
  int aof[2][4], bof[2][4];
#pragma unroll
  for (int kk = 0; kk < 2; ++kk)
#pragma unroll
    for (int m = 0; m < 4; ++m) {
      aof[kk][m] = (wr * 64 + m * 16 + l15) * 128 + ((kk * 64 + lhi * 16) ^ sw);
      bof[kk][m] = (wc * 64 + m * 16 + l15) * 128 + ((kk * 64 + lhi * 16) ^ sw);
    }
  f32x4 acc[4][4] = {};
  STAGE3(0, 0);
  STAGE3(1, 1);
  for (int t = 0; t < nkt; t += 3) {
    TILE3(t, 0, 2);
    TILE3(t + 1, 1, 0);
    TILE3(t + 2, 2, 1);
  }
  // ---- epilogue ----
#pragma unroll
  for (int m_ = 0; m_ < 4; ++m_) {
    const int m0 = bm + wr * 64 + m_ * 16 + (lhi << 2);
#pragma unroll
    for (int nn = 0; nn < 4; ++nn) {
      const int col = bn + wc * 64 + nn * 16 + l15;
      if constexpr (EPI == 2) {
        const float bb = bias[col];
#pragma unroll
        for (int rr = 0; rr < 4; ++rr) {
          float tt = acc[m_][nn][rr] + bb;
          tt = 0.5f * tt * (1.0f + erff(tt * 0.70710678118654752f));
          outb[(size_t)(m0 + rr) * N + col] = f2b(tt);
        }
      } else if constexpr (EPI == 5) {
        const int sec = col / CC;
        const int rn = col - sec * CC;
        const int hh = rn >> 6, d = rn & 63;
        const int b = m0 >> 10, t0 = m0 & 1023;
        if (sec == 2) {
          ushort4 w;
          w.x = f2b(acc[m_][nn][0]); w.y = f2b(acc[m_][nn][1]);
          w.z = f2b(acc[m_][nn][2]); w.w = f2b(acc[m_][nn][3]);
          *(ushort4*)(outb + 2 * QKREG + ((size_t)(b * HH + hh) * 64 + d) * TT + t0) = w;
        } else {
          uint16_t* dst = outb + (size_t)sec * QKREG + ((size_t)(b * HH + hh) * TT + t0) * 64 + d;
#pragma unroll
          for (int rr = 0; rr < 4; ++rr) dst[(size_t)rr * 64] = f2b(acc[m_][nn][rr]);
        }
      } else {  // EPI 7: f32 partial store, bias folded into kp==0
        float* pdst = outf + (size_t)kp * ((size_t)MM * CC);
        const float bb = (kp == 0 && bias) ? bias[col] : 0.f;
#pragma unroll
        for (int rr = 0; rr < 4; ++rr)
          pdst[(size_t)(m0 + rr) * N + col] = acc[m_][nn][rr] + bb;
      }
    }
  }
}

// ---------------- fused causal flash attention ----------------
__global__ __launch_bounds__(256) void attn_k(const uint16_t* __restrict__ qkvh,
                                              uint16_t* __restrict__ ao) {
  __shared__ __align__(16) uint16_t Ks[64 * 64], Vs[64 * 64];
  __shared__ __align__(16) uint16_t Ps[4][16 * 64];
  const int tid = threadIdx.x, lane = tid & 63, wid = tid >> 6;
  const int qt = (TT / 64 - 1) - blockIdx.x / (BB * HH);
  const int bh = blockIdx.x % (BB * HH);
  const uint16_t* qb = qkvh + (size_t)bh * (TT * 64);
  const uint16_t* kb = qkvh + QKREG + (size_t)bh * (TT * 64);
  const uint16_t* vb = qkvh + 2 * QKREG + (size_t)bh * ((size_t)64 * TT);
  const int l15 = lane & 15, lhi = lane >> 4;
  bf16x8 qf[2];
  {
    const uint16_t* qr = qb + (size_t)(qt * 64 + wid * 16 + l15) * 64 + lhi * 8;
    qf[0] = *(const bf16x8*)qr;
    qf[1] = *(const bf16x8*)(qr + 32);
  }
  const int c0 = tid, c1 = tid + 256;
  const int r0 = c0 >> 3, r1 = c1 >> 3;
  const int cb0 = (c0 & 7) * 16, cb1 = (c1 & 7) * 16;
  const int ph0 = r0 * 128 + (cb0 ^ ((r0 & 7) << 4));
  const int ph1 = r1 * 128 + (cb1 ^ ((r1 & 7) << 4));

  uint4 kr0, kr1, vr0, vr1;
  kr0 = *(const uint4*)(kb + (size_t)r0 * 64 + cb0 / 2);
  kr1 = *(const uint4*)(kb + (size_t)r1 * 64 + cb1 / 2);
  vr0 = *(const uint4*)(vb + (size_t)r0 * TT + cb0 / 2);
  vr1 = *(const uint4*)(vb + (size_t)r1 * TT + cb1 / 2);
  *(uint4*)((char*)Ks + ph0) = kr0;
  *(uint4*)((char*)Ks + ph1) = kr1;
  *(uint4*)((char*)Vs + ph0) = vr0;
  *(uint4*)((char*)Vs + ph1) = vr1;
  __syncthreads();

  f32x4 oacc[4] = {};
  float mrun[4] = {-INFINITY, -INFINITY, -INFINITY, -INFINITY};
  float lrun[4] = {0.f, 0.f, 0.f, 0.f};
  char* pb = (char*)Ps[wid];

  for (int j = 0; j <= qt; ++j) {
    const bool more = (j < qt);
    if (more) {
      const int jn = (j + 1) * 64;
      kr0 = *(const uint4*)(kb + (size_t)(jn + r0) * 64 + cb0 / 2);
      kr1 = *(const uint4*)(kb + (size_t)(jn + r1) * 64 + cb1 / 2);
      vr0 = *(const uint4*)(vb + (size_t)r0 * TT + jn + cb0 / 2);
      vr1 = *(const uint4*)(vb + (size_t)r1 * TT + jn + cb1 / 2);
    }
    f32x4 s4[4] = {};
    __builtin_amdgcn_s_setprio(1);
#pragma unroll
    for (int kk = 0; kk < 2; ++kk) {
      const int cbyte = kk * 64 + lhi * 16;
#pragma unroll
      for (int nt = 0; nt < 4; ++nt) {
        const int krow = nt * 16 + l15;
        const bf16x8 kf = *(const bf16x8*)((char*)Ks + krow * 128 + (cbyte ^ ((krow & 7) << 4)));
        s4[nt] = mfma16(qf[kk], kf, s4[nt]);
      }
    }
    __builtin_amdgcn_s_setprio(0);
    const bool diag = (j == qt);
    float alpha[4];
#pragma unroll
    for (int r = 0; r < 4; ++r) {
      const int qg = qt * 64 + wid * 16 + (lhi << 2) + r;
      float mx = -INFINITY;
#pragma unroll
      for (int nt = 0; nt < 4; ++nt) {
        float v = s4[nt][r] * 0.125f;
        if (diag && (j * 64 + nt * 16 + l15) > qg) v = -INFINITY;
        s4[nt][r] = v;
        mx = fmaxf(mx, v);
      }
#pragma unroll
      for (int m = 1; m < 16; m <<= 1) mx = fmaxf(mx, __shfl_xor(mx, m, 16));
      const float mnew = fmaxf(mrun[r], mx);
      alpha[r] = __expf(mrun[r] - mnew);
      float ps = 0.f;
#pragma unroll
      for (int nt = 0; nt < 4; ++nt) {
        const float pp = __expf(s4[nt][r] - mnew);
        s4[nt][r] = pp;
        ps += pp;
      }
#pragma unroll
      for (int m = 1; m < 16; m <<= 1) ps += __shfl_xor(ps, m, 16);
      lrun[r] = lrun[r] * alpha[r] + ps;
      mrun[r] = mnew;
    }
#pragma unroll
    for (int dt = 0; dt < 4; ++dt)
#pragma unroll
      for (int r = 0; r < 4; ++r) oacc[dt][r] *= alpha[r];
#pragma unroll
    for (int r = 0; r < 4; ++r) {
      const int prow = (lhi << 2) + r;
      const int swp = (prow & 7) << 4;
#pragma unroll
      for (int nt = 0; nt < 4; ++nt) {
        const int cb = (nt * 16 + l15) * 2;
        *(uint16_t*)(pb + prow * 128 + (cb ^ swp)) = f2b(s4[nt][r]);
      }
    }
    __builtin_amdgcn_s_setprio(1);
#pragma unroll
    for (int kk = 0; kk < 2; ++kk) {
      const int cbyte = kk * 64 + lhi * 16;
      const bf16x8 pf = *(const bf16x8*)(pb + l15 * 128 + (cbyte ^ ((l15 & 7) << 4)));
#pragma unroll
      for (int dt = 0; dt < 4; ++dt) {
        const int vrow = dt * 16 + l15;
        const bf16x8 vf = *(const bf16x8*)((char*)Vs + vrow * 128 + (cbyte ^ ((vrow & 7) << 4)));
        oacc[dt] = mfma16(pf, vf, oacc[dt]);
      }
    }
    __builtin_amdgcn_s_setprio(0);
    __syncthreads();
    if (more) {
      *(uint4*)((char*)Ks + ph0) = kr0;
      *(uint4*)((char*)Ks + ph1) = kr1;
      *(uint4*)((char*)Vs + ph0) = vr0;
      *(uint4*)((char*)Vs + ph1) = vr1;
    }
    __syncthreads();
  }
#pragma unroll
  for (int dt = 0; dt < 4; ++dt) {
#pragma unroll
    for (int r = 0; r < 4; ++r) {
      const int q = qt * 64 + wid * 16 + (lhi << 2) + r;
      const float v = oacc[dt][r] / lrun[r];
      ao[(size_t)((bh / HH) * TT + q) * CC + (bh % HH) * HDIM + dt * 16 + l15] = f2b(v);
    }
  }
}

extern "C" void kernel_launch(void* const* d_in, const int* in_sizes, int n_in,
                              void* d_out, int out_size, void* d_ws, size_t ws_size,
                              hipStream_t stream) {
  (void)in_sizes; (void)n_in; (void)out_size;
  const int*   idx  = (const int*)d_in[0];
  const float* tok  = (const float*)d_in[1];
  const float* pos  = (const float*)d_in[2];
  const float* Wqkv = (const float*)d_in[3];
  const float* Wpro = (const float*)d_in[4];
  const float* W1   = (const float*)d_in[5];
  const float* b1   = (const float*)d_in[6];
  const float* W2   = (const float*)d_in[7];
  const float* b2   = (const float*)d_in[8];
  const float* g1   = (const float*)d_in[9];
  const float* be1  = (const float*)d_in[10];
  const float* g2   = (const float*)d_in[11];
  const float* be2  = (const float*)d_in[12];
  const float* gf   = (const float*)d_in[13];
  const float* bfb  = (const float*)d_in[14];
  float* out = (float*)d_out;

  char* p = (char*)d_ws;
  float* x = (float*)p;            p += (size_t)MM * CC * 4;
  uint16_t* act = (uint16_t*)p;    p += (size_t)MM * CC * 2;
  uint16_t* big = (uint16_t*)p;    p += (size_t)MM * DFF * 2;
  uint16_t* wq = (uint16_t*)p;     p += (size_t)CC * 3 * CC * 2;
  uint16_t* wp = (uint16_t*)p;     p += (size_t)CC * CC * 2;
  uint16_t* w1 = (uint16_t*)p;     p += (size_t)CC * DFF * 2;
  uint16_t* w2 = (uint16_t*)p;     p += (size_t)DFF * CC * 2;
  uint16_t* tokb = (uint16_t*)p;   p += (size_t)VV * CC * 2;
  float* part = (float*)p;         p += (size_t)2 * MM * CC * 4;   // split-K partials
  const bool roomy = ws_size >= (size_t)(p - (char*)d_ws);

  cvt4_k<<<dim3((VV * CC / 4 + 255) / 256), 256, 0, stream>>>(tok, tokb, VV * CC / 4);
  embed_k<<<dim3(MM * (CC / 4) / 256), 256, 0, stream>>>(idx, tok, pos, x);
  ln_k<<<dim3(MM / 4), 256, 0, stream>>>(x, g1, be1, act);   // LN1 for layer 0
  for (int l = 0; l < LNUM; ++l) {
    tconv_k<<<dim3(CC / 32, 3 * CC / 32), 256, 0, stream>>>(Wqkv + (size_t)l * CC * 3 * CC, wq, CC, 3 * CC);
    tconv_k<<<dim3(CC / 32, CC / 32), 256, 0, stream>>>(Wpro + (size_t)l * CC * CC, wp, CC, CC);
    tconv_k<<<dim3(CC / 32, DFF / 32), 256, 0, stream>>>(W1 + (size_t)l * CC * DFF, w1, CC, DFF);
    tconv_k<<<dim3(DFF / 32, CC / 32), 256, 0, stream>>>(W2 + (size_t)l * DFF * CC, w2, DFF, CC);
    // QKV: M=8192, N=2304, K=768  -> 32x18 = 576 blocks
    gemm3_k<5><<<dim3((MM / 256) * (3 * CC / 128)), 512, 0, stream>>>(
        act, wq, 3 * CC, CC, 3 * CC / 128, 1, nullptr, big, nullptr);
    attn_k<<<dim3((TT / 64) * BB * HH), 256, 0, stream>>>(big, act);
    if (roomy) {
      // proj: split-K=2 partials -> lnr (x += p0+p1, LN2)
      gemm3_k<7><<<dim3((MM / 256) * (CC / 128) * 2), 512, 0, stream>>>(
          act, wp, CC, CC, CC / 128, 2, nullptr, nullptr, part);
      lnr_k<<<dim3(MM / 4), 256, 0, stream>>>(x, part, part + (size_t)MM * CC,
                                              g2 + (size_t)l * CC, be2 + (size_t)l * CC, act);
    } else {
      gemm_k<3><<<dim3(MM / 128, CC / 128), 256, 0, stream>>>(act, wp, CC, CC, nullptr, x, nullptr, nullptr);
      ln_k<<<dim3(MM / 4), 256, 0, stream>>>(x, g2 + (size_t)l * CC, be2 + (size_t)l * CC, act);
    }
    // W1 + GELU: M=8192, N=3072, K=768 -> 32x24 = 768 blocks
    gemm3_k<2><<<dim3((MM / 256) * (DFF / 128)), 512, 0, stream>>>(
        act, w1, DFF, CC, DFF / 128, 1, b1 + (size_t)l * DFF, big, nullptr);
    const float* ng = (l + 1 < LNUM) ? g1 + (size_t)(l + 1) * CC : gf;
    const float* nb = (l + 1 < LNUM) ? be1 + (size_t)(l + 1) * CC : bfb;
    if (roomy) {
      // W2: split-K=2 partials -> lnr (x += p0+p1, next LN)
      gemm3_k<7><<<dim3((MM / 256) * (CC / 128) * 2), 512, 0, stream>>>(
          big, w2, CC, DFF, CC / 128, 2, b2 + (size_t)l * CC, nullptr, part);
      lnr_k<<<dim3(MM / 4), 256, 0, stream>>>(x, part, part + (size_t)MM * CC, ng, nb, act);
    } else {
      gemm_k<4><<<dim3(MM / 128, CC / 128), 256, 0, stream>>>(big, w2, CC, DFF, b2 + (size_t)l * CC, x, nullptr, nullptr);
      ln_k<<<dim3(MM / 4), 256, 0, stream>>>(x, ng, nb, act);
    }
  }
  gemm_k<1><<<dim3(MM / 128, VV / 128), 256, 0, stream>>>(act, tokb, VV, CC, nullptr, nullptr, nullptr, out);
}

// Round 6
// 1903.054 us; speedup vs baseline: 1.1092x; 1.1092x over previous
//
#include <hip/hip_runtime.h>
#include <hip/hip_bf16.h>
#include <stdint.h>

#define LNUM 6
#define BB 8
#define TT 1024
#define CC 768
#define HH 12
#define HDIM 64
#define DFF 3072
#define VV 512
#define MM (BB*TT)
#define QKREG ((size_t)BB*HH*TT*64)

typedef __bf16 bf16x8 __attribute__((ext_vector_type(8)));
typedef float f32x4 __attribute__((ext_vector_type(4)));

__device__ __forceinline__ uint16_t f2b(float f) {
  uint32_t u = __float_as_uint(f);
  u += 0x7FFFu + ((u >> 16) & 1u);
  return (uint16_t)(u >> 16);
}

__device__ __forceinline__ void gld16(const uint16_t* g, uint16_t* l) {
  __builtin_amdgcn_global_load_lds(
      (const __attribute__((address_space(1))) uint32_t*)g,
      (__attribute__((address_space(3))) uint32_t*)l, 16, 0, 0);
}

__device__ __forceinline__ f32x4 mfma16(bf16x8 a, bf16x8 b, f32x4 c) {
  return __builtin_amdgcn_mfma_f32_16x16x32_bf16(a, b, c, 0, 0, 0);
}

// ---------------- convert f32 -> bf16 ----------------
__global__ __launch_bounds__(256) void cvt4_k(const float* __restrict__ in,
                                              uint16_t* __restrict__ out, int n4) {
  const int gid = blockIdx.x * 256 + threadIdx.x;
  if (gid >= n4) return;
  const float4 v = ((const float4*)in)[gid];
  ushort4 w; w.x = f2b(v.x); w.y = f2b(v.y); w.z = f2b(v.z); w.w = f2b(v.w);
  ((ushort4*)out)[gid] = w;
}

// ---------------- embedding ----------------
__global__ __launch_bounds__(256) void embed_k(const int* __restrict__ idx,
                                               const float* __restrict__ tok,
                                               const float* __restrict__ pos,
                                               float* __restrict__ x) {
  const int gid = blockIdx.x * 256 + threadIdx.x;
  const int row = gid / (CC / 4), c4 = gid % (CC / 4);
  const int t = row & (TT - 1);
  const int tkn = idx[row];
  const float4 a = ((const float4*)(tok + (size_t)tkn * CC))[c4];
  const float4 q = ((const float4*)(pos + (size_t)t * CC))[c4];
  ((float4*)(x + (size_t)row * CC))[c4] =
      make_float4(a.x + q.x, a.y + q.y, a.z + q.z, a.w + q.w);
}

// ---------------- layernorm: fp32 in -> bf16 out ----------------
__global__ __launch_bounds__(256) void ln_k(const float* __restrict__ x,
                                            const float* __restrict__ gamma,
                                            const float* __restrict__ beta,
                                            uint16_t* __restrict__ o) {
  const int lane = threadIdx.x & 63, wid = threadIdx.x >> 6;
  const int row = blockIdx.x * 4 + wid;
  const float4* xr = (const float4*)(x + (size_t)row * CC);
  float4 v[3]; float s = 0.f, sq = 0.f;
#pragma unroll
  for (int i = 0; i < 3; ++i) {
    v[i] = xr[lane + i * 64];
    s += v[i].x + v[i].y + v[i].z + v[i].w;
    sq += v[i].x * v[i].x + v[i].y * v[i].y + v[i].z * v[i].z + v[i].w * v[i].w;
  }
#pragma unroll
  for (int m = 1; m < 64; m <<= 1) { s += __shfl_xor(s, m, 64); sq += __shfl_xor(sq, m, 64); }
  const float mu = s * (1.f / 768.f);
  const float rstd = rsqrtf(sq * (1.f / 768.f) - mu * mu + 1e-5f);
  ushort4* orow = (ushort4*)(o + (size_t)row * CC);
#pragma unroll
  for (int i = 0; i < 3; ++i) {
    const int c4 = lane + i * 64;
    const float4 gg = ((const float4*)gamma)[c4];
    const float4 bb = ((const float4*)beta)[c4];
    ushort4 w;
    w.x = f2b((v[i].x - mu) * rstd * gg.x + bb.x);
    w.y = f2b((v[i].y - mu) * rstd * gg.y + bb.y);
    w.z = f2b((v[i].z - mu) * rstd * gg.z + bb.z);
    w.w = f2b((v[i].w - mu) * rstd * gg.w + bb.w);
    orow[c4] = w;
  }
}

// ------- layernorm + partial-sum reduce: x += p0+p1; o = LN(x)  -------
__global__ __launch_bounds__(256) void lnr_k(float* __restrict__ x,
                                             const float* __restrict__ p0,
                                             const float* __restrict__ p1,
                                             const float* __restrict__ gamma,
                                             const float* __restrict__ beta,
                                             uint16_t* __restrict__ o) {
  const int lane = threadIdx.x & 63, wid = threadIdx.x >> 6;
  const int row = blockIdx.x * 4 + wid;
  float4* xr = (float4*)(x + (size_t)row * CC);
  const float4* pr0 = (const float4*)(p0 + (size_t)row * CC);
  const float4* pr1 = (const float4*)(p1 + (size_t)row * CC);
  float4 v[3]; float s = 0.f, sq = 0.f;
#pragma unroll
  for (int i = 0; i < 3; ++i) {
    const int c4 = lane + i * 64;
    float4 a = xr[c4];
    const float4 q0 = pr0[c4];
    const float4 q1 = pr1[c4];
    a.x += q0.x + q1.x; a.y += q0.y + q1.y;
    a.z += q0.z + q1.z; a.w += q0.w + q1.w;
    xr[c4] = a;
    v[i] = a;
    s += a.x + a.y + a.z + a.w;
    sq += a.x * a.x + a.y * a.y + a.z * a.z + a.w * a.w;
  }
#pragma unroll
  for (int m = 1; m < 64; m <<= 1) { s += __shfl_xor(s, m, 64); sq += __shfl_xor(sq, m, 64); }
  const float mu = s * (1.f / 768.f);
  const float rstd = rsqrtf(sq * (1.f / 768.f) - mu * mu + 1e-5f);
  ushort4* orow = (ushort4*)(o + (size_t)row * CC);
#pragma unroll
  for (int i = 0; i < 3; ++i) {
    const int c4 = lane + i * 64;
    const float4 gg = ((const float4*)gamma)[c4];
    const float4 bb = ((const float4*)beta)[c4];
    ushort4 w;
    w.x = f2b((v[i].x - mu) * rstd * gg.x + bb.x);
    w.y = f2b((v[i].y - mu) * rstd * gg.y + bb.y);
    w.z = f2b((v[i].z - mu) * rstd * gg.z + bb.z);
    w.w = f2b((v[i].w - mu) * rstd * gg.w + bb.w);
    orow[c4] = w;
  }
}

// ---------------- transpose+convert weights ----------------
__global__ __launch_bounds__(256) void tconv_k(const float* __restrict__ in,
                                               uint16_t* __restrict__ out, int K, int N) {
  __shared__ float tile[32][33];
  const int kt = blockIdx.x * 32, nt = blockIdx.y * 32;
  const int tx = threadIdx.x & 31, ty = threadIdx.x >> 5;
#pragma unroll
  for (int i = 0; i < 32; i += 8)
    tile[ty + i][tx] = in[(size_t)(kt + ty + i) * N + nt + tx];
  __syncthreads();
#pragma unroll
  for (int i = 0; i < 32; i += 8)
    out[(size_t)(nt + ty + i) * K + kt + tx] = f2b(tile[tx][ty + i]);
}

// ---------------- old 128x128 GEMM (proj, logits) ----------------
// EPI: 1 = f32 store; 3 = resid +=; 4 = resid += (+bias)
template <int EPI>
__global__ __launch_bounds__(256) void gemm_k(const uint16_t* __restrict__ A,
                                              const uint16_t* __restrict__ Bt,
                                              int N, int K,
                                              const float* __restrict__ bias,
                                              float* __restrict__ resid,
                                              uint16_t* __restrict__ outb,
                                              float* __restrict__ outf) {
  __shared__ __align__(16) uint16_t As[128 * 32];
  __shared__ __align__(16) uint16_t Bs[128 * 32];
  const int lane = threadIdx.x & 63, wid = threadIdx.x >> 6;
  const int wm = wid >> 1, wn = wid & 1;
  const int bm = blockIdx.x * 128, bn = blockIdx.y * 128;
  const int rsub = lane >> 2, csub = (lane & 3) * 8;
  f32x4 acc[4][4] = {};
  for (int k0 = 0; k0 < K; k0 += 32) {
#pragma unroll
    for (int q = 0; q < 2; ++q) {
      const int ch = wid * 2 + q;
      gld16(A + (size_t)(bm + ch * 16 + rsub) * K + k0 + csub, &As[ch * 512]);
      gld16(Bt + (size_t)(bn + ch * 16 + rsub) * K + k0 + csub, &Bs[ch * 512]);
    }
    __syncthreads();
    bf16x8 a[4], b[4];
#pragma unroll
    for (int i = 0; i < 4; ++i) {
      a[i] = *(const bf16x8*)&As[(wm * 64 + i * 16 + (lane & 15)) * 32 + (lane >> 4) * 8];
      b[i] = *(const bf16x8*)&Bs[(wn * 64 + i * 16 + (lane & 15)) * 32 + (lane >> 4) * 8];
    }
#pragma unroll
    for (int i = 0; i < 4; ++i)
#pragma unroll
      for (int j = 0; j < 4; ++j)
        acc[i][j] = mfma16(a[i], b[j], acc[i][j]);
    __syncthreads();
  }
#pragma unroll
  for (int i = 0; i < 4; ++i) {
    const int m0 = bm + wm * 64 + i * 16 + ((lane >> 4) << 2);
#pragma unroll
    for (int j = 0; j < 4; ++j) {
      const int n = bn + wn * 64 + j * 16 + (lane & 15);
#pragma unroll
      for (int r = 0; r < 4; ++r) {
        const size_t o = (size_t)(m0 + r) * N + n;
        const float v = acc[i][j][r];
        if constexpr (EPI == 1) {
          outf[o] = v;
        } else if constexpr (EPI == 3) {
          resid[o] += v;
        } else if constexpr (EPI == 4) {
          resid[o] += v + bias[n];
        }
      }
    }
  }
}

// ======== 256x128-tile, BK=64, triple-buffered, depth-2 prefetch GEMM ========
// RAW s_barrier only in the K-loop (NO __syncthreads: compiler would emit a
// vmcnt(0) drain and kill the pipeline). Safety argument:
//  - barrier A: every wave's ds_reads of the buffer being overwritten retired
//    (lgkmcnt(0) inside each PHASE3 before its MFMAs) -> WAR safe.
//  - vmcnt(12) after staging tile T+2: waits exactly tile T's 6 loads
//    (issued 2 full tiles ago >= HBM latency) -> per-wave completion.
//  - barrier B: all waves passed their own vmcnt -> tile T fully visible.
// EPI: 2 = bias+GELU -> bf16; 5 = qkv split; 7 = f32 partial store (+bias kp0)

#define STAGE3(BQ, T)                                                     \
  do {                                                                    \
    const int ko_ = (T) * 64;                                             \
    gld16(gA + ko_,                 &ldsA[BQ][0 * 4096 + (tid << 3)]);    \
    gld16(gA + ko_ + 64 * (size_t)K,  &ldsA[BQ][1 * 4096 + (tid << 3)]);  \
    gld16(gA + ko_ + 128 * (size_t)K, &ldsA[BQ][2 * 4096 + (tid << 3)]);  \
    gld16(gA + ko_ + 192 * (size_t)K, &ldsA[BQ][3 * 4096 + (tid << 3)]);  \
    gld16(gB + ko_,                 &ldsB[BQ][0 * 4096 + (tid << 3)]);    \
    gld16(gB + ko_ + 64 * (size_t)K,  &ldsB[BQ][1 * 4096 + (tid << 3)]);  \
  } while (0)

#define PHASE3(AB, BBp, KK)                                               \
  {                                                                       \
    bf16x8 a_[4], b_[4];                                                  \
    _Pragma("unroll") for (int m_ = 0; m_ < 4; ++m_)                      \
      a_[m_] = *(const bf16x8*)((AB) + aof[KK][m_]);                      \
    _Pragma("unroll") for (int n_ = 0; n_ < 4; ++n_)                      \
      b_[n_] = *(const bf16x8*)((BBp) + bof[KK][n_]);                     \
    asm volatile("s_waitcnt lgkmcnt(0)" ::: "memory");                    \
    __builtin_amdgcn_sched_barrier(0);                                    \
    __builtin_amdgcn_s_setprio(1);                                        \
    _Pragma("unroll") for (int m_ = 0; m_ < 4; ++m_)                      \
      _Pragma("unroll") for (int n_ = 0; n_ < 4; ++n_)                    \
        acc[m_][n_] = mfma16(a_[m_], b_[n_], acc[m_][n_]);                \
    __builtin_amdgcn_s_setprio(0);                                        \
  }

#define TILE3(T, CUR, SB)                                                 \
  do {                                                                    \
    __builtin_amdgcn_s_barrier();                                         \
    if ((T) + 2 < nkt) {                                                  \
      STAGE3(SB, (T) + 2);                                                \
      asm volatile("s_waitcnt vmcnt(12)" ::: "memory");                   \
    } else if ((T) + 1 < nkt) {                                           \
      asm volatile("s_waitcnt vmcnt(6)" ::: "memory");                    \
    } else {                                                              \
      asm volatile("s_waitcnt vmcnt(0)" ::: "memory");                    \
    }                                                                     \
    __builtin_amdgcn_sched_barrier(0);                                    \
    __builtin_amdgcn_s_barrier();                                         \
    {                                                                     \
      const char* Ab_ = (const char*)ldsA[CUR];                           \
      const char* Bb_ = (const char*)ldsB[CUR];                           \
      PHASE3(Ab_, Bb_, 0)                                                 \
      PHASE3(Ab_, Bb_, 1)                                                 \
    }                                                                     \
  } while (0)

template <int EPI>
__global__ __launch_bounds__(512, 2) void gemm3_k(const uint16_t* __restrict__ A,
                                                  const uint16_t* __restrict__ Bt,
                                                  int N, int K, int nbn, int kparts,
                                                  const float* __restrict__ bias,
                                                  uint16_t* __restrict__ outb,
                                                  float* __restrict__ outf) {
  __shared__ uint16_t ldsA[3][16384];
  __shared__ uint16_t ldsB[3][8192];
  const int tid = threadIdx.x, lane = tid & 63, wid = tid >> 6;
  const int l15 = lane & 15, lhi = lane >> 4;
  const int wr = wid >> 1, wc = wid & 1;
  int id = blockIdx.x;
  const int nwg = gridDim.x;
  id = (id & 7) * (nwg >> 3) + (id >> 3);  // XCD swizzle; all grids %8==0
  const int nbmn = nwg / kparts;
  const int kp = id / nbmn;
  const int rid = id - kp * nbmn;
  const int im = rid / nbn, in = rid - im * nbn;
  const int bm = im * 256, bn = in * 128;
  const int Ksub = K / kparts, k0base = kp * Ksub, nkt = Ksub >> 6;  // nkt%3==0
  const int arow = tid >> 3;
  const int aslot = (tid & 7) ^ (arow & 7);
  const uint16_t* gA = A + (size_t)(bm + arow) * K + k0base + aslot * 8;
  const uint16_t* gB = Bt + (size_t)(bn + arow) * K + k0base + aslot * 8;
  const int sw = (l15 & 7) << 4;
  int aof[2][4], bof[2][4];
#pragma unroll
  for (int kk = 0; kk < 2; ++kk)
#pragma unroll
    for (int m = 0; m < 4; ++m) {
      aof[kk][m] = (wr * 64 + m * 16 + l15) * 128 + ((kk * 64 + lhi * 16) ^ sw);
      bof[kk][m] = (wc * 64 + m * 16 + l15) * 128 + ((kk * 64 + lhi * 16) ^ sw);
    }
  f32x4 acc[4][4] = {};
  STAGE3(0, 0);
  STAGE3(1, 1);
  for (int t = 0; t < nkt; t += 3) {
    TILE3(t, 0, 2);
    TILE3(t + 1, 1, 0);
    TILE3(t + 2, 2, 1);
  }
  // ---- epilogue ----
#pragma unroll
  for (int m_ = 0; m_ < 4; ++m_) {
    const int m0 = bm + wr * 64 + m_ * 16 + (lhi << 2);
#pragma unroll
    for (int nn = 0; nn < 4; ++nn) {
      const int col = bn + wc * 64 + nn * 16 + l15;
      if constexpr (EPI == 2) {
        const float bb = bias[col];
#pragma unroll
        for (int rr = 0; rr < 4; ++rr) {
          float tt = acc[m_][nn][rr] + bb;
          tt = 0.5f * tt * (1.0f + erff(tt * 0.70710678118654752f));
          outb[(size_t)(m0 + rr) * N + col] = f2b(tt);
        }
      } else if constexpr (EPI == 5) {
        const int sec = col / CC;
        const int rn = col - sec * CC;
        const int hh = rn >> 6, d = rn & 63;
        const int b = m0 >> 10, t0 = m0 & 1023;
        if (sec == 2) {
          ushort4 w;
          w.x = f2b(acc[m_][nn][0]); w.y = f2b(acc[m_][nn][1]);
          w.z = f2b(acc[m_][nn][2]); w.w = f2b(acc[m_][nn][3]);
          *(ushort4*)(outb + 2 * QKREG + ((size_t)(b * HH + hh) * 64 + d) * TT + t0) = w;
        } else {
          uint16_t* dst = outb + (size_t)sec * QKREG + ((size_t)(b * HH + hh) * TT + t0) * 64 + d;
#pragma unroll
          for (int rr = 0; rr < 4; ++rr) dst[(size_t)rr * 64] = f2b(acc[m_][nn][rr]);
        }
      } else {  // EPI 7: f32 partial store, bias folded into kp==0
        float* pdst = outf + (size_t)kp * ((size_t)MM * CC);
        const float bb = (kp == 0 && bias) ? bias[col] : 0.f;
#pragma unroll
        for (int rr = 0; rr < 4; ++rr)
          pdst[(size_t)(m0 + rr) * N + col] = acc[m_][nn][rr] + bb;
      }
    }
  }
}

// ---------------- fused causal flash attention ----------------
__global__ __launch_bounds__(256) void attn_k(const uint16_t* __restrict__ qkvh,
                                              uint16_t* __restrict__ ao) {
  __shared__ __align__(16) uint16_t Ks[64 * 64], Vs[64 * 64];
  __shared__ __align__(16) uint16_t Ps[4][16 * 64];
  const int tid = threadIdx.x, lane = tid & 63, wid = tid >> 6;
  const int qt = (TT / 64 - 1) - blockIdx.x / (BB * HH);
  const int bh = blockIdx.x % (BB * HH);
  const uint16_t* qb = qkvh + (size_t)bh * (TT * 64);
  const uint16_t* kb = qkvh + QKREG + (size_t)bh * (TT * 64);
  const uint16_t* vb = qkvh + 2 * QKREG + (size_t)bh * ((size_t)64 * TT);
  const int l15 = lane & 15, lhi = lane >> 4;
  bf16x8 qf[2];
  {
    const uint16_t* qr = qb + (size_t)(qt * 64 + wid * 16 + l15) * 64 + lhi * 8;
    qf[0] = *(const bf16x8*)qr;
    qf[1] = *(const bf16x8*)(qr + 32);
  }
  const int c0 = tid, c1 = tid + 256;
  const int r0 = c0 >> 3, r1 = c1 >> 3;
  const int cb0 = (c0 & 7) * 16, cb1 = (c1 & 7) * 16;
  const int ph0 = r0 * 128 + (cb0 ^ ((r0 & 7) << 4));
  const int ph1 = r1 * 128 + (cb1 ^ ((r1 & 7) << 4));

  uint4 kr0, kr1, vr0, vr1;
  kr0 = *(const uint4*)(kb + (size_t)r0 * 64 + cb0 / 2);
  kr1 = *(const uint4*)(kb + (size_t)r1 * 64 + cb1 / 2);
  vr0 = *(const uint4*)(vb + (size_t)r0 * TT + cb0 / 2);
  vr1 = *(const uint4*)(vb + (size_t)r1 * TT + cb1 / 2);
  *(uint4*)((char*)Ks + ph0) = kr0;
  *(uint4*)((char*)Ks + ph1) = kr1;
  *(uint4*)((char*)Vs + ph0) = vr0;
  *(uint4*)((char*)Vs + ph1) = vr1;
  __syncthreads();

  f32x4 oacc[4] = {};
  float mrun[4] = {-INFINITY, -INFINITY, -INFINITY, -INFINITY};
  float lrun[4] = {0.f, 0.f, 0.f, 0.f};
  char* pb = (char*)Ps[wid];

  for (int j = 0; j <= qt; ++j) {
    const bool more = (j < qt);
    if (more) {
      const int jn = (j + 1) * 64;
      kr0 = *(const uint4*)(kb + (size_t)(jn + r0) * 64 + cb0 / 2);
      kr1 = *(const uint4*)(kb + (size_t)(jn + r1) * 64 + cb1 / 2);
      vr0 = *(const uint4*)(vb + (size_t)r0 * TT + jn + cb0 / 2);
      vr1 = *(const uint4*)(vb + (size_t)r1 * TT + jn + cb1 / 2);
    }
    f32x4 s4[4] = {};
    __builtin_amdgcn_s_setprio(1);
#pragma unroll
    for (int kk = 0; kk < 2; ++kk) {
      const int cbyte = kk * 64 + lhi * 16;
#pragma unroll
      for (int nt = 0; nt < 4; ++nt) {
        const int krow = nt * 16 + l15;
        const bf16x8 kf = *(const bf16x8*)((char*)Ks + krow * 128 + (cbyte ^ ((krow & 7) << 4)));
        s4[nt] = mfma16(qf[kk], kf, s4[nt]);
      }
    }
    __builtin_amdgcn_s_setprio(0);
    const bool diag = (j == qt);
    float alpha[4];
#pragma unroll
    for (int r = 0; r < 4; ++r) {
      const int qg = qt * 64 + wid * 16 + (lhi << 2) + r;
      float mx = -INFINITY;
#pragma unroll
      for (int nt = 0; nt < 4; ++nt) {
        float v = s4[nt][r] * 0.125f;
        if (diag && (j * 64 + nt * 16 + l15) > qg) v = -INFINITY;
        s4[nt][r] = v;
        mx = fmaxf(mx, v);
      }
#pragma unroll
      for (int m = 1; m < 16; m <<= 1) mx = fmaxf(mx, __shfl_xor(mx, m, 16));
      const float mnew = fmaxf(mrun[r], mx);
      alpha[r] = __expf(mrun[r] - mnew);
      float ps = 0.f;
#pragma unroll
      for (int nt = 0; nt < 4; ++nt) {
        const float pp = __expf(s4[nt][r] - mnew);
        s4[nt][r] = pp;
        ps += pp;
      }
#pragma unroll
      for (int m = 1; m < 16; m <<= 1) ps += __shfl_xor(ps, m, 16);
      lrun[r] = lrun[r] * alpha[r] + ps;
      mrun[r] = mnew;
    }
#pragma unroll
    for (int dt = 0; dt < 4; ++dt)
#pragma unroll
      for (int r = 0; r < 4; ++r) oacc[dt][r] *= alpha[r];
#pragma unroll
    for (int r = 0; r < 4; ++r) {
      const int prow = (lhi << 2) + r;
      const int swp = (prow & 7) << 4;
#pragma unroll
      for (int nt = 0; nt < 4; ++nt) {
        const int cb = (nt * 16 + l15) * 2;
        *(uint16_t*)(pb + prow * 128 + (cb ^ swp)) = f2b(s4[nt][r]);
      }
    }
    __builtin_amdgcn_s_setprio(1);
#pragma unroll
    for (int kk = 0; kk < 2; ++kk) {
      const int cbyte = kk * 64 + lhi * 16;
      const bf16x8 pf = *(const bf16x8*)(pb + l15 * 128 + (cbyte ^ ((l15 & 7) << 4)));
#pragma unroll
      for (int dt = 0; dt < 4; ++dt) {
        const int vrow = dt * 16 + l15;
        const bf16x8 vf = *(const bf16x8*)((char*)Vs + vrow * 128 + (cbyte ^ ((vrow & 7) << 4)));
        oacc[dt] = mfma16(pf, vf, oacc[dt]);
      }
    }
    __builtin_amdgcn_s_setprio(0);
    __syncthreads();
    if (more) {
      *(uint4*)((char*)Ks + ph0) = kr0;
      *(uint4*)((char*)Ks + ph1) = kr1;
      *(uint4*)((char*)Vs + ph0) = vr0;
      *(uint4*)((char*)Vs + ph1) = vr1;
    }
    __syncthreads();
  }
#pragma unroll
  for (int dt = 0; dt < 4; ++dt) {
#pragma unroll
    for (int r = 0; r < 4; ++r) {
      const int q = qt * 64 + wid * 16 + (lhi << 2) + r;
      const float v = oacc[dt][r] / lrun[r];
      ao[(size_t)((bh / HH) * TT + q) * CC + (bh % HH) * HDIM + dt * 16 + l15] = f2b(v);
    }
  }
}

extern "C" void kernel_launch(void* const* d_in, const int* in_sizes, int n_in,
                              void* d_out, int out_size, void* d_ws, size_t ws_size,
                              hipStream_t stream) {
  (void)in_sizes; (void)n_in; (void)out_size;
  const int*   idx  = (const int*)d_in[0];
  const float* tok  = (const float*)d_in[1];
  const float* pos  = (const float*)d_in[2];
  const float* Wqkv = (const float*)d_in[3];
  const float* Wpro = (const float*)d_in[4];
  const float* W1   = (const float*)d_in[5];
  const float* b1   = (const float*)d_in[6];
  const float* W2   = (const float*)d_in[7];
  const float* b2   = (const float*)d_in[8];
  const float* g1   = (const float*)d_in[9];
  const float* be1  = (const float*)d_in[10];
  const float* g2   = (const float*)d_in[11];
  const float* be2  = (const float*)d_in[12];
  const float* gf   = (const float*)d_in[13];
  const float* bfb  = (const float*)d_in[14];
  float* out = (float*)d_out;

  char* p = (char*)d_ws;
  float* x = (float*)p;            p += (size_t)MM * CC * 4;
  uint16_t* act = (uint16_t*)p;    p += (size_t)MM * CC * 2;
  uint16_t* big = (uint16_t*)p;    p += (size_t)MM * DFF * 2;
  uint16_t* wq = (uint16_t*)p;     p += (size_t)CC * 3 * CC * 2;
  uint16_t* wp = (uint16_t*)p;     p += (size_t)CC * CC * 2;
  uint16_t* w1 = (uint16_t*)p;     p += (size_t)CC * DFF * 2;
  uint16_t* w2 = (uint16_t*)p;     p += (size_t)DFF * CC * 2;
  uint16_t* tokb = (uint16_t*)p;   p += (size_t)VV * CC * 2;
  float* part = (float*)p;         p += (size_t)2 * MM * CC * 4;   // split-K partials
  const bool roomy = ws_size >= (size_t)(p - (char*)d_ws);

  cvt4_k<<<dim3((VV * CC / 4 + 255) / 256), 256, 0, stream>>>(tok, tokb, VV * CC / 4);
  embed_k<<<dim3(MM * (CC / 4) / 256), 256, 0, stream>>>(idx, tok, pos, x);
  ln_k<<<dim3(MM / 4), 256, 0, stream>>>(x, g1, be1, act);   // LN1 for layer 0
  for (int l = 0; l < LNUM; ++l) {
    tconv_k<<<dim3(CC / 32, 3 * CC / 32), 256, 0, stream>>>(Wqkv + (size_t)l * CC * 3 * CC, wq, CC, 3 * CC);
    tconv_k<<<dim3(CC / 32, CC / 32), 256, 0, stream>>>(Wpro + (size_t)l * CC * CC, wp, CC, CC);
    tconv_k<<<dim3(CC / 32, DFF / 32), 256, 0, stream>>>(W1 + (size_t)l * CC * DFF, w1, CC, DFF);
    tconv_k<<<dim3(DFF / 32, CC / 32), 256, 0, stream>>>(W2 + (size_t)l * DFF * CC, w2, DFF, CC);
    // QKV: M=8192, N=2304, K=768 -> 32x18 = 576 blocks, nkt=12
    gemm3_k<5><<<dim3((MM / 256) * (3 * CC / 128)), 512, 0, stream>>>(
        act, wq, 3 * CC, CC, 3 * CC / 128, 1, nullptr, big, nullptr);
    attn_k<<<dim3((TT / 64) * BB * HH), 256, 0, stream>>>(big, act);
    // proj: best-known path (r4): 128x128 RMW into fp32 residual
    gemm_k<3><<<dim3(MM / 128, CC / 128), 256, 0, stream>>>(act, wp, CC, CC, nullptr, x, nullptr, nullptr);
    ln_k<<<dim3(MM / 4), 256, 0, stream>>>(x, g2 + (size_t)l * CC, be2 + (size_t)l * CC, act);
    // W1 + GELU: M=8192, N=3072, K=768 -> 32x24 = 768 blocks (3 exact rounds), nkt=12
    gemm3_k<2><<<dim3((MM / 256) * (DFF / 128)), 512, 0, stream>>>(
        act, w1, DFF, CC, DFF / 128, 1, b1 + (size_t)l * DFF, big, nullptr);
    const float* ng = (l + 1 < LNUM) ? g1 + (size_t)(l + 1) * CC : gf;
    const float* nb = (l + 1 < LNUM) ? be1 + (size_t)(l + 1) * CC : bfb;
    if (roomy) {
      // W2: split-K=2 partials (nkt=24 each) -> lnr (x += p0+p1, next LN)
      gemm3_k<7><<<dim3((MM / 256) * (CC / 128) * 2), 512, 0, stream>>>(
          big, w2, CC, DFF, CC / 128, 2, b2 + (size_t)l * CC, nullptr, part);
      lnr_k<<<dim3(MM / 4), 256, 0, stream>>>(x, part, part + (size_t)MM * CC, ng, nb, act);
    } else {
      gemm_k<4><<<dim3(MM / 128, CC / 128), 256, 0, stream>>>(big, w2, CC, DFF, b2 + (size_t)l * CC, x, nullptr, nullptr);
      ln_k<<<dim3(MM / 4), 256, 0, stream>>>(x, ng, nb, act);
    }
  }
  gemm_k<1><<<dim3(MM / 128, VV / 128), 256, 0, stream>>>(act, tokb, VV, CC, nullptr, nullptr, nullptr, out);
}

// Round 7
// 1866.372 us; speedup vs baseline: 1.1310x; 1.0197x over previous
//
#include <hip/hip_runtime.h>
#include <hip/hip_bf16.h>
#include <stdint.h>

#define LNUM 6
#define BB 8
#define TT 1024
#define CC 768
#define HH 12
#define HDIM 64
#define DFF 3072
#define VV 512
#define MM (BB*TT)
#define QKREG ((size_t)BB*HH*TT*64)

typedef __bf16 bf16x8 __attribute__((ext_vector_type(8)));
typedef float f32x4 __attribute__((ext_vector_type(4)));

__device__ __forceinline__ uint16_t f2b(float f) {
  uint32_t u = __float_as_uint(f);
  u += 0x7FFFu + ((u >> 16) & 1u);
  return (uint16_t)(u >> 16);
}

__device__ __forceinline__ void gld16(const uint16_t* g, uint16_t* l) {
  __builtin_amdgcn_global_load_lds(
      (const __attribute__((address_space(1))) uint32_t*)g,
      (__attribute__((address_space(3))) uint32_t*)l, 16, 0, 0);
}

__device__ __forceinline__ f32x4 mfma16(bf16x8 a, bf16x8 b, f32x4 c) {
  return __builtin_amdgcn_mfma_f32_16x16x32_bf16(a, b, c, 0, 0, 0);
}

// ---------------- convert f32 -> bf16 ----------------
__global__ __launch_bounds__(256) void cvt4_k(const float* __restrict__ in,
                                              uint16_t* __restrict__ out, int n4) {
  const int gid = blockIdx.x * 256 + threadIdx.x;
  if (gid >= n4) return;
  const float4 v = ((const float4*)in)[gid];
  ushort4 w; w.x = f2b(v.x); w.y = f2b(v.y); w.z = f2b(v.z); w.w = f2b(v.w);
  ((ushort4*)out)[gid] = w;
}

// ---------------- embedding ----------------
__global__ __launch_bounds__(256) void embed_k(const int* __restrict__ idx,
                                               const float* __restrict__ tok,
                                               const float* __restrict__ pos,
                                               float* __restrict__ x) {
  const int gid = blockIdx.x * 256 + threadIdx.x;
  const int row = gid / (CC / 4), c4 = gid % (CC / 4);
  const int t = row & (TT - 1);
  const int tkn = idx[row];
  const float4 a = ((const float4*)(tok + (size_t)tkn * CC))[c4];
  const float4 q = ((const float4*)(pos + (size_t)t * CC))[c4];
  ((float4*)(x + (size_t)row * CC))[c4] =
      make_float4(a.x + q.x, a.y + q.y, a.z + q.z, a.w + q.w);
}

// ---------------- layernorm: fp32 in -> bf16 out ----------------
__global__ __launch_bounds__(256) void ln_k(const float* __restrict__ x,
                                            const float* __restrict__ gamma,
                                            const float* __restrict__ beta,
                                            uint16_t* __restrict__ o) {
  const int lane = threadIdx.x & 63, wid = threadIdx.x >> 6;
  const int row = blockIdx.x * 4 + wid;
  const float4* xr = (const float4*)(x + (size_t)row * CC);
  float4 v[3]; float s = 0.f, sq = 0.f;
#pragma unroll
  for (int i = 0; i < 3; ++i) {
    v[i] = xr[lane + i * 64];
    s += v[i].x + v[i].y + v[i].z + v[i].w;
    sq += v[i].x * v[i].x + v[i].y * v[i].y + v[i].z * v[i].z + v[i].w * v[i].w;
  }
#pragma unroll
  for (int m = 1; m < 64; m <<= 1) { s += __shfl_xor(s, m, 64); sq += __shfl_xor(sq, m, 64); }
  const float mu = s * (1.f / 768.f);
  const float rstd = rsqrtf(sq * (1.f / 768.f) - mu * mu + 1e-5f);
  ushort4* orow = (ushort4*)(o + (size_t)row * CC);
#pragma unroll
  for (int i = 0; i < 3; ++i) {
    const int c4 = lane + i * 64;
    const float4 gg = ((const float4*)gamma)[c4];
    const float4 bb = ((const float4*)beta)[c4];
    ushort4 w;
    w.x = f2b((v[i].x - mu) * rstd * gg.x + bb.x);
    w.y = f2b((v[i].y - mu) * rstd * gg.y + bb.y);
    w.z = f2b((v[i].z - mu) * rstd * gg.z + bb.z);
    w.w = f2b((v[i].w - mu) * rstd * gg.w + bb.w);
    orow[c4] = w;
  }
}

// ------- layernorm + partial-sum reduce: x += p0+p1; o = LN(x)  -------
__global__ __launch_bounds__(256) void lnr_k(float* __restrict__ x,
                                             const float* __restrict__ p0,
                                             const float* __restrict__ p1,
                                             const float* __restrict__ gamma,
                                             const float* __restrict__ beta,
                                             uint16_t* __restrict__ o) {
  const int lane = threadIdx.x & 63, wid = threadIdx.x >> 6;
  const int row = blockIdx.x * 4 + wid;
  float4* xr = (float4*)(x + (size_t)row * CC);
  const float4* pr0 = (const float4*)(p0 + (size_t)row * CC);
  const float4* pr1 = (const float4*)(p1 + (size_t)row * CC);
  float4 v[3]; float s = 0.f, sq = 0.f;
#pragma unroll
  for (int i = 0; i < 3; ++i) {
    const int c4 = lane + i * 64;
    float4 a = xr[c4];
    const float4 q0 = pr0[c4];
    const float4 q1 = pr1[c4];
    a.x += q0.x + q1.x; a.y += q0.y + q1.y;
    a.z += q0.z + q1.z; a.w += q0.w + q1.w;
    xr[c4] = a;
    v[i] = a;
    s += a.x + a.y + a.z + a.w;
    sq += a.x * a.x + a.y * a.y + a.z * a.z + a.w * a.w;
  }
#pragma unroll
  for (int m = 1; m < 64; m <<= 1) { s += __shfl_xor(s, m, 64); sq += __shfl_xor(sq, m, 64); }
  const float mu = s * (1.f / 768.f);
  const float rstd = rsqrtf(sq * (1.f / 768.f) - mu * mu + 1e-5f);
  ushort4* orow = (ushort4*)(o + (size_t)row * CC);
#pragma unroll
  for (int i = 0; i < 3; ++i) {
    const int c4 = lane + i * 64;
    const float4 gg = ((const float4*)gamma)[c4];
    const float4 bb = ((const float4*)beta)[c4];
    ushort4 w;
    w.x = f2b((v[i].x - mu) * rstd * gg.x + bb.x);
    w.y = f2b((v[i].y - mu) * rstd * gg.y + bb.y);
    w.z = f2b((v[i].z - mu) * rstd * gg.z + bb.z);
    w.w = f2b((v[i].w - mu) * rstd * gg.w + bb.w);
    orow[c4] = w;
  }
}

// ---------------- transpose+convert weights ----------------
__global__ __launch_bounds__(256) void tconv_k(const float* __restrict__ in,
                                               uint16_t* __restrict__ out, int K, int N) {
  __shared__ float tile[32][33];
  const int kt = blockIdx.x * 32, nt = blockIdx.y * 32;
  const int tx = threadIdx.x & 31, ty = threadIdx.x >> 5;
#pragma unroll
  for (int i = 0; i < 32; i += 8)
    tile[ty + i][tx] = in[(size_t)(kt + ty + i) * N + nt + tx];
  __syncthreads();
#pragma unroll
  for (int i = 0; i < 32; i += 8)
    out[(size_t)(nt + ty + i) * K + kt + tx] = f2b(tile[tx][ty + i]);
}

// ---------------- old 128x128 GEMM (proj, logits) ----------------
// EPI: 1 = f32 store; 3 = resid +=; 4 = resid += (+bias)
template <int EPI>
__global__ __launch_bounds__(256) void gemm_k(const uint16_t* __restrict__ A,
                                              const uint16_t* __restrict__ Bt,
                                              int N, int K,
                                              const float* __restrict__ bias,
                                              float* __restrict__ resid,
                                              uint16_t* __restrict__ outb,
                                              float* __restrict__ outf) {
  __shared__ __align__(16) uint16_t As[128 * 32];
  __shared__ __align__(16) uint16_t Bs[128 * 32];
  const int lane = threadIdx.x & 63, wid = threadIdx.x >> 6;
  const int wm = wid >> 1, wn = wid & 1;
  const int bm = blockIdx.x * 128, bn = blockIdx.y * 128;
  const int rsub = lane >> 2, csub = (lane & 3) * 8;
  f32x4 acc[4][4] = {};
  for (int k0 = 0; k0 < K; k0 += 32) {
#pragma unroll
    for (int q = 0; q < 2; ++q) {
      const int ch = wid * 2 + q;
      gld16(A + (size_t)(bm + ch * 16 + rsub) * K + k0 + csub, &As[ch * 512]);
      gld16(Bt + (size_t)(bn + ch * 16 + rsub) * K + k0 + csub, &Bs[ch * 512]);
    }
    __syncthreads();
    bf16x8 a[4], b[4];
#pragma unroll
    for (int i = 0; i < 4; ++i) {
      a[i] = *(const bf16x8*)&As[(wm * 64 + i * 16 + (lane & 15)) * 32 + (lane >> 4) * 8];
      b[i] = *(const bf16x8*)&Bs[(wn * 64 + i * 16 + (lane & 15)) * 32 + (lane >> 4) * 8];
    }
#pragma unroll
    for (int i = 0; i < 4; ++i)
#pragma unroll
      for (int j = 0; j < 4; ++j)
        acc[i][j] = mfma16(a[i], b[j], acc[i][j]);
    __syncthreads();
  }
#pragma unroll
  for (int i = 0; i < 4; ++i) {
    const int m0 = bm + wm * 64 + i * 16 + ((lane >> 4) << 2);
#pragma unroll
    for (int j = 0; j < 4; ++j) {
      const int n = bn + wn * 64 + j * 16 + (lane & 15);
#pragma unroll
      for (int r = 0; r < 4; ++r) {
        const size_t o = (size_t)(m0 + r) * N + n;
        const float v = acc[i][j][r];
        if constexpr (EPI == 1) {
          outf[o] = v;
        } else if constexpr (EPI == 3) {
          resid[o] += v;
        } else if constexpr (EPI == 4) {
          resid[o] += v + bias[n];
        }
      }
    }
  }
}

// ======== 256x128-tile, BK=64, triple-buffered, depth-2 prefetch GEMM ========
// K-loop uses asm barriers only (no __syncthreads -> no compiler vmcnt(0) drain).
// Tile body = ONE compiler-scheduled region: 32 ds_reads + 32 MFMAs, compiler
// inserts fine-grained lgkmcnt so reads overlap MFMAs (no forced drain).
// Correctness:
//  - barrier A = "lgkmcnt(0); s_barrier": wave's LDS reads retired -> WAR-safe
//    for the staging that follows (gld16 writes buffer read last tile).
//  - vmcnt(12) after staging T+2 waits exactly tile T's 6 loads (issued 2
//    tiles = ~2 full tile-times ago >= HBM latency).
//  - barrier B = "s_barrier" + memory clobber: pins tile-T ds_reads below the
//    cross-wave visibility point.
// EPI: 2 = bias+GELU -> bf16; 5 = qkv split; 7 = f32 partial store (+bias kp0)

#define STAGE3(BQ, T)                                                     \
  do {                                                                    \
    const int ko_ = (T) * 64;                                             \
    gld16(gA + ko_,                 &ldsA[BQ][0 * 4096 + (tid << 3)]);    \
    gld16(gA + ko_ + 64 * (size_t)K,  &ldsA[BQ][1 * 4096 + (tid << 3)]);  \
    gld16(gA + ko_ + 128 * (size_t)K, &ldsA[BQ][2 * 4096 + (tid << 3)]);  \
    gld16(gA + ko_ + 192 * (size_t)K, &ldsA[BQ][3 * 4096 + (tid << 3)]);  \
    gld16(gB + ko_,                 &ldsB[BQ][0 * 4096 + (tid << 3)]);    \
    gld16(gB + ko_ + 64 * (size_t)K,  &ldsB[BQ][1 * 4096 + (tid << 3)]);  \
  } while (0)

#define TILE3(T, CUR, SB)                                                 \
  do {                                                                    \
    asm volatile("s_waitcnt lgkmcnt(0)\n\ts_barrier" ::: "memory");       \
    if ((T) + 2 < nkt) {                                                  \
      STAGE3(SB, (T) + 2);                                                \
      asm volatile("s_waitcnt vmcnt(12)" ::: "memory");                   \
    } else if ((T) + 1 < nkt) {                                           \
      asm volatile("s_waitcnt vmcnt(6)" ::: "memory");                    \
    } else {                                                              \
      asm volatile("s_waitcnt vmcnt(0)" ::: "memory");                    \
    }                                                                     \
    asm volatile("s_barrier" ::: "memory");                               \
    {                                                                     \
      const char* Ab_ = (const char*)ldsA[CUR];                           \
      const char* Bb_ = (const char*)ldsB[CUR];                           \
      bf16x8 a0_[4], b0_[4], a1_[4], b1_[4];                              \
      _Pragma("unroll") for (int q_ = 0; q_ < 4; ++q_) {                  \
        a0_[q_] = *(const bf16x8*)(Ab_ + aof[0][q_]);                     \
        b0_[q_] = *(const bf16x8*)(Bb_ + bof[0][q_]);                     \
        a1_[q_] = *(const bf16x8*)(Ab_ + aof[1][q_]);                     \
        b1_[q_] = *(const bf16x8*)(Bb_ + bof[1][q_]);                     \
      }                                                                   \
      _Pragma("unroll") for (int m_ = 0; m_ < 4; ++m_)                    \
        _Pragma("unroll") for (int n_ = 0; n_ < 4; ++n_)                  \
          acc[m_][n_] = mfma16(a0_[m_], b0_[n_], acc[m_][n_]);            \
      _Pragma("unroll") for (int m_ = 0; m_ < 4; ++m_)                    \
        _Pragma("unroll") for (int n_ = 0; n_ < 4; ++n_)                  \
          acc[m_][n_] = mfma16(a1_[m_], b1_[n_], acc[m_][n_]);            \
    }                                                                     \
  } while (0)

template <int EPI>
__global__ __launch_bounds__(512, 2) void gemm3_k(const uint16_t* __restrict__ A,
                                                  const uint16_t* __restrict__ Bt,
                                                  int N, int K, int nbn, int kparts,
                                                  const float* __restrict__ bias,
                                                  uint16_t* __restrict__ outb,
                                                  float* __restrict__ outf) {
  __shared__ uint16_t ldsA[3][16384];
  __shared__ uint16_t ldsB[3][8192];
  const int tid = threadIdx.x, lane = tid & 63, wid = tid >> 6;
  const int l15 = lane & 15, lhi = lane >> 4;
  const int wr = wid >> 1, wc = wid & 1;
  int id = blockIdx.x;
  const int nwg = gridDim.x;
  id = (id & 7) * (nwg >> 3) + (id >> 3);  // XCD swizzle; all grids %8==0
  const int nbmn = nwg / kparts;
  const int kp = id / nbmn;
  const int rid = id - kp * nbmn;
  const int im = rid / nbn, in = rid - im * nbn;
  const int bm = im * 256, bn = in * 128;
  const int Ksub = K / kparts, k0base = kp * Ksub, nkt = Ksub >> 6;  // nkt%3==0
  const int arow = tid >> 3;
  const int aslot = (tid & 7) ^ (arow & 7);
  const uint16_t* gA = A + (size_t)(bm + arow) * K + k0base + aslot * 8;
  const uint16_t* gB = Bt + (size_t)(bn + arow) * K + k0base + aslot * 8;
  const int sw = (l15 & 7) << 4;
  int aof[2][4], bof[2][4];
#pragma unroll
  for (int kk = 0; kk < 2; ++kk)
#pragma unroll
    for (int m = 0; m < 4; ++m) {
      aof[kk][m] = (wr * 64 + m * 16 + l15) * 128 + ((kk * 64 + lhi * 16) ^ sw);
      bof[kk][m] = (wc * 64 + m * 16 + l15) * 128 + ((kk * 64 + lhi * 16) ^ sw);
    }
  f32x4 acc[4][4] = {};
  STAGE3(0, 0);
  STAGE3(1, 1);
  for (int t = 0; t < nkt; t += 3) {
    TILE3(t, 0, 2);
    TILE3(t + 1, 1, 0);
    TILE3(t + 2, 2, 1);
  }
  // ---- epilogue ----
#pragma unroll
  for (int m_ = 0; m_ < 4; ++m_) {
    const int m0 = bm + wr * 64 + m_ * 16 + (lhi << 2);
#pragma unroll
    for (int nn = 0; nn < 4; ++nn) {
      const int col = bn + wc * 64 + nn * 16 + l15;
      if constexpr (EPI == 2) {
        const float bb = bias[col];
#pragma unroll
        for (int rr = 0; rr < 4; ++rr) {
          float tt = acc[m_][nn][rr] + bb;
          tt = 0.5f * tt * (1.0f + erff(tt * 0.70710678118654752f));
          outb[(size_t)(m0 + rr) * N + col] = f2b(tt);
        }
      } else if constexpr (EPI == 5) {
        const int sec = col / CC;
        const int rn = col - sec * CC;
        const int hh = rn >> 6, d = rn & 63;
        const int b = m0 >> 10, t0 = m0 & 1023;
        if (sec == 2) {
          ushort4 w;
          w.x = f2b(acc[m_][nn][0]); w.y = f2b(acc[m_][nn][1]);
          w.z = f2b(acc[m_][nn][2]); w.w = f2b(acc[m_][nn][3]);
          *(ushort4*)(outb + 2 * QKREG + ((size_t)(b * HH + hh) * 64 + d) * TT + t0) = w;
        } else {
          uint16_t* dst = outb + (size_t)sec * QKREG + ((size_t)(b * HH + hh) * TT + t0) * 64 + d;
#pragma unroll
          for (int rr = 0; rr < 4; ++rr) dst[(size_t)rr * 64] = f2b(acc[m_][nn][rr]);
        }
      } else {  // EPI 7: f32 partial store, bias folded into kp==0
        float* pdst = outf + (size_t)kp * ((size_t)MM * CC);
        const float bb = (kp == 0 && bias) ? bias[col] : 0.f;
#pragma unroll
        for (int rr = 0; rr < 4; ++rr)
          pdst[(size_t)(m0 + rr) * N + col] = acc[m_][nn][rr] + bb;
      }
    }
  }
}

// ---------------- fused causal flash attention ----------------
__global__ __launch_bounds__(256) void attn_k(const uint16_t* __restrict__ qkvh,
                                              uint16_t* __restrict__ ao) {
  __shared__ __align__(16) uint16_t Ks[64 * 64], Vs[64 * 64];
  __shared__ __align__(16) uint16_t Ps[4][16 * 64];
  const int tid = threadIdx.x, lane = tid & 63, wid = tid >> 6;
  const int qt = (TT / 64 - 1) - blockIdx.x / (BB * HH);
  const int bh = blockIdx.x % (BB * HH);
  const uint16_t* qb = qkvh + (size_t)bh * (TT * 64);
  const uint16_t* kb = qkvh + QKREG + (size_t)bh * (TT * 64);
  const uint16_t* vb = qkvh + 2 * QKREG + (size_t)bh * ((size_t)64 * TT);
  const int l15 = lane & 15, lhi = lane >> 4;
  bf16x8 qf[2];
  {
    const uint16_t* qr = qb + (size_t)(qt * 64 + wid * 16 + l15) * 64 + lhi * 8;
    qf[0] = *(const bf16x8*)qr;
    qf[1] = *(const bf16x8*)(qr + 32);
  }
  const int c0 = tid, c1 = tid + 256;
  const int r0 = c0 >> 3, r1 = c1 >> 3;
  const int cb0 = (c0 & 7) * 16, cb1 = (c1 & 7) * 16;
  const int ph0 = r0 * 128 + (cb0 ^ ((r0 & 7) << 4));
  const int ph1 = r1 * 128 + (cb1 ^ ((r1 & 7) << 4));

  uint4 kr0, kr1, vr0, vr1;
  kr0 = *(const uint4*)(kb + (size_t)r0 * 64 + cb0 / 2);
  kr1 = *(const uint4*)(kb + (size_t)r1 * 64 + cb1 / 2);
  vr0 = *(const uint4*)(vb + (size_t)r0 * TT + cb0 / 2);
  vr1 = *(const uint4*)(vb + (size_t)r1 * TT + cb1 / 2);
  *(uint4*)((char*)Ks + ph0) = kr0;
  *(uint4*)((char*)Ks + ph1) = kr1;
  *(uint4*)((char*)Vs + ph0) = vr0;
  *(uint4*)((char*)Vs + ph1) = vr1;
  __syncthreads();

  f32x4 oacc[4] = {};
  float mrun[4] = {-INFINITY, -INFINITY, -INFINITY, -INFINITY};
  float lrun[4] = {0.f, 0.f, 0.f, 0.f};
  char* pb = (char*)Ps[wid];

  for (int j = 0; j <= qt; ++j) {
    const bool more = (j < qt);
    if (more) {
      const int jn = (j + 1) * 64;
      kr0 = *(const uint4*)(kb + (size_t)(jn + r0) * 64 + cb0 / 2);
      kr1 = *(const uint4*)(kb + (size_t)(jn + r1) * 64 + cb1 / 2);
      vr0 = *(const uint4*)(vb + (size_t)r0 * TT + jn + cb0 / 2);
      vr1 = *(const uint4*)(vb + (size_t)r1 * TT + jn + cb1 / 2);
    }
    f32x4 s4[4] = {};
    __builtin_amdgcn_s_setprio(1);
#pragma unroll
    for (int kk = 0; kk < 2; ++kk) {
      const int cbyte = kk * 64 + lhi * 16;
#pragma unroll
      for (int nt = 0; nt < 4; ++nt) {
        const int krow = nt * 16 + l15;
        const bf16x8 kf = *(const bf16x8*)((char*)Ks + krow * 128 + (cbyte ^ ((krow & 7) << 4)));
        s4[nt] = mfma16(qf[kk], kf, s4[nt]);
      }
    }
    __builtin_amdgcn_s_setprio(0);
    const bool diag = (j == qt);
    float alpha[4];
#pragma unroll
    for (int r = 0; r < 4; ++r) {
      const int qg = qt * 64 + wid * 16 + (lhi << 2) + r;
      float mx = -INFINITY;
#pragma unroll
      for (int nt = 0; nt < 4; ++nt) {
        float v = s4[nt][r] * 0.125f;
        if (diag && (j * 64 + nt * 16 + l15) > qg) v = -INFINITY;
        s4[nt][r] = v;
        mx = fmaxf(mx, v);
      }
#pragma unroll
      for (int m = 1; m < 16; m <<= 1) mx = fmaxf(mx, __shfl_xor(mx, m, 16));
      const float mnew = fmaxf(mrun[r], mx);
      alpha[r] = __expf(mrun[r] - mnew);
      float ps = 0.f;
#pragma unroll
      for (int nt = 0; nt < 4; ++nt) {
        const float pp = __expf(s4[nt][r] - mnew);
        s4[nt][r] = pp;
        ps += pp;
      }
#pragma unroll
      for (int m = 1; m < 16; m <<= 1) ps += __shfl_xor(ps, m, 16);
      lrun[r] = lrun[r] * alpha[r] + ps;
      mrun[r] = mnew;
    }
#pragma unroll
    for (int dt = 0; dt < 4; ++dt)
#pragma unroll
      for (int r = 0; r < 4; ++r) oacc[dt][r] *= alpha[r];
#pragma unroll
    for (int r = 0; r < 4; ++r) {
      const int prow = (lhi << 2) + r;
      const int swp = (prow & 7) << 4;
#pragma unroll
      for (int nt = 0; nt < 4; ++nt) {
        const int cb = (nt * 16 + l15) * 2;
        *(uint16_t*)(pb + prow * 128 + (cb ^ swp)) = f2b(s4[nt][r]);
      }
    }
    __builtin_amdgcn_s_setprio(1);
#pragma unroll
    for (int kk = 0; kk < 2; ++kk) {
      const int cbyte = kk * 64 + lhi * 16;
      const bf16x8 pf = *(const bf16x8*)(pb + l15 * 128 + (cbyte ^ ((l15 & 7) << 4)));
#pragma unroll
      for (int dt = 0; dt < 4; ++dt) {
        const int vrow = dt * 16 + l15;
        const bf16x8 vf = *(const bf16x8*)((char*)Vs + vrow * 128 + (cbyte ^ ((vrow & 7) << 4)));
        oacc[dt] = mfma16(pf, vf, oacc[dt]);
      }
    }
    __builtin_amdgcn_s_setprio(0);
    __syncthreads();
    if (more) {
      *(uint4*)((char*)Ks + ph0) = kr0;
      *(uint4*)((char*)Ks + ph1) = kr1;
      *(uint4*)((char*)Vs + ph0) = vr0;
      *(uint4*)((char*)Vs + ph1) = vr1;
    }
    __syncthreads();
  }
#pragma unroll
  for (int dt = 0; dt < 4; ++dt) {
#pragma unroll
    for (int r = 0; r < 4; ++r) {
      const int q = qt * 64 + wid * 16 + (lhi << 2) + r;
      const float v = oacc[dt][r] / lrun[r];
      ao[(size_t)((bh / HH) * TT + q) * CC + (bh % HH) * HDIM + dt * 16 + l15] = f2b(v);
    }
  }
}

extern "C" void kernel_launch(void* const* d_in, const int* in_sizes, int n_in,
                              void* d_out, int out_size, void* d_ws, size_t ws_size,
                              hipStream_t stream) {
  (void)in_sizes; (void)n_in; (void)out_size;
  const int*   idx  = (const int*)d_in[0];
  const float* tok  = (const float*)d_in[1];
  const float* pos  = (const float*)d_in[2];
  const float* Wqkv = (const float*)d_in[3];
  const float* Wpro = (const float*)d_in[4];
  const float* W1   = (const float*)d_in[5];
  const float* b1   = (const float*)d_in[6];
  const float* W2   = (const float*)d_in[7];
  const float* b2   = (const float*)d_in[8];
  const float* g1   = (const float*)d_in[9];
  const float* be1  = (const float*)d_in[10];
  const float* g2   = (const float*)d_in[11];
  const float* be2  = (const float*)d_in[12];
  const float* gf   = (const float*)d_in[13];
  const float* bfb  = (const float*)d_in[14];
  float* out = (float*)d_out;

  char* p = (char*)d_ws;
  float* x = (float*)p;            p += (size_t)MM * CC * 4;
  uint16_t* act = (uint16_t*)p;    p += (size_t)MM * CC * 2;
  uint16_t* big = (uint16_t*)p;    p += (size_t)MM * DFF * 2;
  uint16_t* wq = (uint16_t*)p;     p += (size_t)CC * 3 * CC * 2;
  uint16_t* wp = (uint16_t*)p;     p += (size_t)CC * CC * 2;
  uint16_t* w1 = (uint16_t*)p;     p += (size_t)CC * DFF * 2;
  uint16_t* w2 = (uint16_t*)p;     p += (size_t)DFF * CC * 2;
  uint16_t* tokb = (uint16_t*)p;   p += (size_t)VV * CC * 2;
  float* part = (float*)p;         p += (size_t)2 * MM * CC * 4;   // split-K partials
  const bool roomy = ws_size >= (size_t)(p - (char*)d_ws);

  cvt4_k<<<dim3((VV * CC / 4 + 255) / 256), 256, 0, stream>>>(tok, tokb, VV * CC / 4);
  embed_k<<<dim3(MM * (CC / 4) / 256), 256, 0, stream>>>(idx, tok, pos, x);
  ln_k<<<dim3(MM / 4), 256, 0, stream>>>(x, g1, be1, act);   // LN1 for layer 0
  for (int l = 0; l < LNUM; ++l) {
    tconv_k<<<dim3(CC / 32, 3 * CC / 32), 256, 0, stream>>>(Wqkv + (size_t)l * CC * 3 * CC, wq, CC, 3 * CC);
    tconv_k<<<dim3(CC / 32, CC / 32), 256, 0, stream>>>(Wpro + (size_t)l * CC * CC, wp, CC, CC);
    tconv_k<<<dim3(CC / 32, DFF / 32), 256, 0, stream>>>(W1 + (size_t)l * CC * DFF, w1, CC, DFF);
    tconv_k<<<dim3(DFF / 32, CC / 32), 256, 0, stream>>>(W2 + (size_t)l * DFF * CC, w2, DFF, CC);
    // QKV: M=8192, N=2304, K=768 -> 32x18 = 576 blocks, nkt=12
    gemm3_k<5><<<dim3((MM / 256) * (3 * CC / 128)), 512, 0, stream>>>(
        act, wq, 3 * CC, CC, 3 * CC / 128, 1, nullptr, big, nullptr);
    attn_k<<<dim3((TT / 64) * BB * HH), 256, 0, stream>>>(big, act);
    // proj: 128x128 RMW into fp32 residual
    gemm_k<3><<<dim3(MM / 128, CC / 128), 256, 0, stream>>>(act, wp, CC, CC, nullptr, x, nullptr, nullptr);
    ln_k<<<dim3(MM / 4), 256, 0, stream>>>(x, g2 + (size_t)l * CC, be2 + (size_t)l * CC, act);
    // W1 + GELU: M=8192, N=3072, K=768 -> 32x24 = 768 blocks (3 exact rounds), nkt=12
    gemm3_k<2><<<dim3((MM / 256) * (DFF / 128)), 512, 0, stream>>>(
        act, w1, DFF, CC, DFF / 128, 1, b1 + (size_t)l * DFF, big, nullptr);
    const float* ng = (l + 1 < LNUM) ? g1 + (size_t)(l + 1) * CC : gf;
    const float* nb = (l + 1 < LNUM) ? be1 + (size_t)(l + 1) * CC : bfb;
    if (roomy) {
      // W2: split-K=2 partials (nkt=24 each) -> lnr (x += p0+p1, next LN)
      gemm3_k<7><<<dim3((MM / 256) * (CC / 128) * 2), 512, 0, stream>>>(
          big, w2, CC, DFF, CC / 128, 2, b2 + (size_t)l * CC, nullptr, part);
      lnr_k<<<dim3(MM / 4), 256, 0, stream>>>(x, part, part + (size_t)MM * CC, ng, nb, act);
    } else {
      gemm_k<4><<<dim3(MM / 128, CC / 128), 256, 0, stream>>>(big, w2, CC, DFF, b2 + (size_t)l * CC, x, nullptr, nullptr);
      ln_k<<<dim3(MM / 4), 256, 0, stream>>>(x, ng, nb, act);
    }
  }
  gemm_k<1><<<dim3(MM / 128, VV / 128), 256, 0, stream>>>(act, tokb, VV, CC, nullptr, nullptr, nullptr, out);
}